// Round 1
// baseline (9.734 us; speedup 1.0000x reference)
//
#include <hip/hip_runtime.h>

#define NQ 8
#define ROWS (16 * 4096)   // BATCH * SEQ
#define EMBED 768

__global__ __launch_bounds__(256) void qfe_kernel(const float* __restrict__ x,
                                                  const float* __restrict__ theta,
                                                  float* __restrict__ out) {
    int row = blockIdx.x * blockDim.x + threadIdx.x;
    if (row >= ROWS) return;

    // cos(theta) — uniform across threads, compiler turns these into s_loads
    float ct[NQ];
#pragma unroll
    for (int j = 0; j < NQ; ++j) ct[j] = cosf(theta[j]);

    const float4* xr = reinterpret_cast<const float4*>(x + (size_t)row * EMBED);
    float4 a0 = xr[0];
    float4 a1 = xr[1];

    float4 o0, o1;
    o0.x = cosf(a0.x) * ct[0];
    o0.y = cosf(a0.y) * ct[1];
    o0.z = cosf(a0.z) * ct[2];
    o0.w = cosf(a0.w) * ct[3];
    o1.x = cosf(a1.x) * ct[4];
    o1.y = cosf(a1.y) * ct[5];
    o1.z = cosf(a1.z) * ct[6];
    o1.w = cosf(a1.w) * ct[7];

    float4* orow = reinterpret_cast<float4*>(out + (size_t)row * NQ);
    orow[0] = o0;
    orow[1] = o1;
}

extern "C" void kernel_launch(void* const* d_in, const int* in_sizes, int n_in,
                              void* d_out, int out_size, void* d_ws, size_t ws_size,
                              hipStream_t stream) {
    const float* x     = (const float*)d_in[0];
    const float* theta = (const float*)d_in[1];
    float* out         = (float*)d_out;

    dim3 block(256);
    dim3 grid((ROWS + 255) / 256);
    qfe_kernel<<<grid, block, 0, stream>>>(x, theta, out);
}